// Round 1
// baseline (8015.972 us; speedup 1.0000x reference)
//
#include <hip/hip_runtime.h>

// VanillaRNN B=64,S=2048,I=128,H=512,O=128. ALL inputs fp32; OUTPUT fp32
// (outputs [64][2048][128] then h_final [64][512], flat-concatenated fp32).
//
// 2-batch-interleaved pair kernel: 64 blocks x 512 threads; block pair
// (2i,2i+1) owns batches p=2i, q=2i+1. Each WG holds its 256x512 W_rec
// slice + W_in slice + 64x512 W_out slice in VGPRs as fp16 (v_dot2_f32_f16,
// fp32 accumulate) and computes that slice for BOTH batches per step,
// phase-interleaved so each cross-WG h-exchange round trip (~2-3k cycles,
// MALL-coherent) is hidden under the other batch's GEMV phase:
//   compute_p -> publish_p -> poll_q(t) -> barrier ->
//   compute_q -> publish_q -> poll_p(t+1) -> barrier
// h buffers are parity double-buffered in LDS so no extra intra-step barrier
// is needed between reads of h^t and writes of h^{t+1}.
// Exchange: tagged u64 agent-scope atomic stores (tag = t+1 in hi32),
// parity-double-buffered slots. Tag overwrite safety: a WG can publish tag
// T+2 into a slot only after consuming data its partner publishes later in
// program order than the partner's poll of tag T (barrier-ordered).
// ws usage: [B][2 wg][2 parity][128] u64 = 256 KiB. Poison 0xAA.. never
// matches tags 1..2048, so re-poisoned ws is safe.
// 64 WGs <= 256 CUs -> all co-resident, exchange cannot deadlock.

typedef _Float16 half2_t __attribute__((ext_vector_type(2)));
typedef _Float16 half8_t __attribute__((ext_vector_type(8)));
typedef float    float2_t __attribute__((ext_vector_type(2)));
typedef float    float4_t __attribute__((ext_vector_type(4)));

#define BB 64
#define SS 2048
#define IN 128
#define HH 512
#define OO 128

using u32 = unsigned int;
using u64 = unsigned long long;

__device__ __forceinline__ float fdot2f(half2_t a, half2_t b, float c) {
#if __has_builtin(__builtin_amdgcn_fdot2)
    return __builtin_amdgcn_fdot2(a, b, c, false);
#else
    return c + (float)a[0] * (float)b[0] + (float)a[1] * (float)b[1];
#endif
}
__device__ __forceinline__ half2_t h2(float a, float b) {
    return half2_t{(_Float16)a, (_Float16)b};
}

// ---- full GEMV slice for one batch: recurrence + fused input proj +
//      output row, then 8-lane butterfly reduce. Uses/clobbers acc[4], oa.
#define GEMV_PHASE(HB, XB)                                                   \
    do {                                                                     \
        const half2_t* hb_ = &(HB)[c * 36];                                  \
        _Pragma("unroll")                                                    \
        for (int kb = 0; kb < 8; ++kb) {                                     \
            const half8_t hv = *(const half8_t*)(hb_ + kb * 4);              \
            const half2_t p0 = __builtin_shufflevector(hv, hv, 0, 1);        \
            const half2_t p1 = __builtin_shufflevector(hv, hv, 2, 3);        \
            const half2_t p2 = __builtin_shufflevector(hv, hv, 4, 5);        \
            const half2_t p3 = __builtin_shufflevector(hv, hv, 6, 7);        \
            _Pragma("unroll")                                                \
            for (int jj = 0; jj < 4; ++jj) {                                 \
                acc[jj] = fdot2f(wr[jj][kb * 4 + 0], p0, acc[jj]);           \
                acc[jj] = fdot2f(wr[jj][kb * 4 + 1], p1, acc[jj]);           \
                acc[jj] = fdot2f(wr[jj][kb * 4 + 2], p2, acc[jj]);           \
                acc[jj] = fdot2f(wr[jj][kb * 4 + 3], p3, acc[jj]);           \
            }                                                                \
            oa = fdot2f(wo[kb * 4 + 0], p0, oa);                             \
            oa = fdot2f(wo[kb * 4 + 1], p1, oa);                             \
            oa = fdot2f(wo[kb * 4 + 2], p2, oa);                             \
            oa = fdot2f(wo[kb * 4 + 3], p3, oa);                             \
        }                                                                    \
        {                                                                    \
            const half2_t* xb_ = &(XB)[c * 12];                              \
            const half8_t xv0 = *(const half8_t*)(xb_);                      \
            const half8_t xv1 = *(const half8_t*)(xb_ + 4);                  \
            const half2_t x0 = __builtin_shufflevector(xv0, xv0, 0, 1);      \
            const half2_t x1 = __builtin_shufflevector(xv0, xv0, 2, 3);      \
            const half2_t x2 = __builtin_shufflevector(xv0, xv0, 4, 5);      \
            const half2_t x3 = __builtin_shufflevector(xv0, xv0, 6, 7);      \
            const half2_t x4 = __builtin_shufflevector(xv1, xv1, 0, 1);      \
            const half2_t x5 = __builtin_shufflevector(xv1, xv1, 2, 3);      \
            const half2_t x6 = __builtin_shufflevector(xv1, xv1, 4, 5);      \
            const half2_t x7 = __builtin_shufflevector(xv1, xv1, 6, 7);      \
            _Pragma("unroll")                                                \
            for (int jj = 0; jj < 4; ++jj) {                                 \
                acc[jj] = fdot2f(wi[jj][0], x0, acc[jj]);                    \
                acc[jj] = fdot2f(wi[jj][1], x1, acc[jj]);                    \
                acc[jj] = fdot2f(wi[jj][2], x2, acc[jj]);                    \
                acc[jj] = fdot2f(wi[jj][3], x3, acc[jj]);                    \
                acc[jj] = fdot2f(wi[jj][4], x4, acc[jj]);                    \
                acc[jj] = fdot2f(wi[jj][5], x5, acc[jj]);                    \
                acc[jj] = fdot2f(wi[jj][6], x6, acc[jj]);                    \
                acc[jj] = fdot2f(wi[jj][7], x7, acc[jj]);                    \
            }                                                                \
        }                                                                    \
        _Pragma("unroll")                                                    \
        for (int jj = 0; jj < 4; ++jj) {                                     \
            float v = acc[jj];                                               \
            v += __shfl_xor(v, 1);                                           \
            v += __shfl_xor(v, 2);                                           \
            v += __shfl_xor(v, 4);                                           \
            acc[jj] = v;                                                     \
        }                                                                    \
        oa += __shfl_xor(oa, 1);                                             \
        oa += __shfl_xor(oa, 2);                                             \
        oa += __shfl_xor(oa, 4);                                             \
    } while (0)

// ---- write output row t-1 (c==1 lane, sum is wave-replicated), tanh +
//      own-slice LDS write + tagged publish (c==0 lanes).
#define FINALIZE(BATCH, BSEL, T)                                             \
    do {                                                                     \
        const int pn_ = ((T) + 1) & 1;                                       \
        if (c == 1 && (T) > 0)                                               \
            outp[(size_t)((BATCH) * SS + ((T) - 1)) * OO + og] = oa + bo;    \
        if (c == 0) {                                                        \
            const float v0 = tanhf(acc[0] + bias[0]);                        \
            const float v1 = tanhf(acc[1] + bias[1]);                        \
            const float v2 = tanhf(acc[2] + bias[2]);                        \
            const float v3 = tanhf(acc[3] + bias[3]);                        \
            const half2_t ha = h2(v0, v1);                                   \
            const half2_t hc = h2(v2, v3);                                   \
            const int kg = w * 256 + g * 4;                                  \
            const int pos = (kg >> 6) * 36 + ((kg & 63) >> 1);               \
            hbuf[BSEL][pn_][pos]     = ha;                                   \
            hbuf[BSEL][pn_][pos + 1] = hc;                                   \
            const u64 taghi = ((u64)(u32)((T) + 1)) << 32;                   \
            const int sbase = (((BATCH) * 2 + w) * 2 + pn_) * 128 + g * 2;   \
            __hip_atomic_store(&hex[sbase],                                  \
                               taghi | (u64)__builtin_bit_cast(u32, ha),     \
                               __ATOMIC_RELAXED, __HIP_MEMORY_SCOPE_AGENT);  \
            __hip_atomic_store(&hex[sbase + 1],                              \
                               taghi | (u64)__builtin_bit_cast(u32, hc),     \
                               __ATOMIC_RELAXED, __HIP_MEMORY_SCOPE_AGENT);  \
            if ((T) == SS - 1)                                               \
                *(float4_t*)(&hfinal[(BATCH) * HH + w * 256 + g * 4]) =      \
                    float4_t{v0, v1, v2, v3};                                \
        }                                                                    \
    } while (0)

// ---- pull partner's 256 h values with tag TAG into hbuf[BSEL][TAG&1].
#define POLL(BATCH, BSEL, TAG)                                               \
    do {                                                                     \
        if (tid < 128) {                                                     \
            const int pw_ = 1 - w;                                           \
            const int sidx =                                                 \
                (((BATCH) * 2 + pw_) * 2 + ((TAG) & 1)) * 128 + tid;         \
            u64 v;                                                           \
            do {                                                             \
                v = __hip_atomic_load(&hex[sidx], __ATOMIC_RELAXED,          \
                                      __HIP_MEMORY_SCOPE_AGENT);             \
            } while ((u32)(v >> 32) != (u32)(TAG));                          \
            const int kg = pw_ * 256 + tid * 2;                              \
            hbuf[BSEL][(TAG) & 1][(kg >> 6) * 36 + ((kg & 63) >> 1)] =       \
                __builtin_bit_cast(half2_t, (u32)v);                         \
        }                                                                    \
    } while (0)

__global__ __launch_bounds__(512, 2) void rnn_fused(
    const float* __restrict__ inputs,   // [B][S][I]
    const float* __restrict__ h0,       // [B][H]
    const float* __restrict__ W_in,     // [H][I]
    const float* __restrict__ W_in_b,   // [H]
    const float* __restrict__ W_rec,    // [H][H]
    const float* __restrict__ W_out,    // [O][H]
    const float* __restrict__ W_out_b,  // [O]
    float* __restrict__ outp,           // fp32 [B][S][O]
    float* __restrict__ hfinal,         // fp32 [B][H]
    u64* __restrict__ hex)              // [B][2][2][128]
{
    const int tid = threadIdx.x;
    const int pr = blockIdx.x >> 1;    // pair index 0..31
    const int w  = blockIdx.x & 1;     // which half of H this WG produces
    const int bp = pr * 2;             // batch p
    const int bq = pr * 2 + 1;         // batch q
    const int c  = tid & 7;            // k-chunk (64 h values each)
    const int g  = tid >> 3;           // j-quad / o index
    const int og = w * 64 + g;         // this thread-group's output column

    // h as half2, chunk-strided 36 dwords (bank-conflict-free), indexed
    // [batch][parity]. x rows likewise [batch][parity].
    __shared__ __align__(16) half2_t hbuf[2][2][288];
    __shared__ __align__(16) half2_t xh[2][2][96];

    // ---- persistent weights in VGPRs (fp32 -> fp16 once)
    half2_t wr[4][32];   // W_rec[jg][c*64 + 2m..]
    half2_t wi[4][8];    // W_in [jg][c*16 + 2m..]
    half2_t wo[32];      // W_out[og][c*64 + 2m..]
    float bias[4];

    #pragma unroll
    for (int jj = 0; jj < 4; ++jj) {
        const int jg = w * 256 + g * 4 + jj;
        const float4_t* rrow = (const float4_t*)(W_rec + jg * HH + c * 64);
        #pragma unroll
        for (int m = 0; m < 16; ++m) {
            const float4_t u = rrow[m];
            wr[jj][m * 2 + 0] = h2(u[0], u[1]);
            wr[jj][m * 2 + 1] = h2(u[2], u[3]);
        }
        const float4_t* irow = (const float4_t*)(W_in + jg * IN + c * 16);
        #pragma unroll
        for (int m = 0; m < 4; ++m) {
            const float4_t u = irow[m];
            wi[jj][m * 2 + 0] = h2(u[0], u[1]);
            wi[jj][m * 2 + 1] = h2(u[2], u[3]);
        }
        bias[jj] = W_in_b[jg];
    }
    {
        const float4_t* orow = (const float4_t*)(W_out + og * HH + c * 64);
        #pragma unroll
        for (int m = 0; m < 16; ++m) {
            const float4_t u = orow[m];
            wo[m * 2 + 0] = h2(u[0], u[1]);
            wo[m * 2 + 1] = h2(u[2], u[3]);
        }
    }
    const float bo = W_out_b[og];

    // ---- init LDS: h = h0 for both batches (parity 0), x row 0 both
    if (tid < 256) {
        const float2_t u = *(const float2_t*)(h0 + bp * HH + tid * 2);
        const int k = tid * 2;
        hbuf[0][0][(k >> 6) * 36 + ((k & 63) >> 1)] = h2(u[0], u[1]);
    } else {
        const int e = tid - 256;
        const float2_t u = *(const float2_t*)(h0 + bq * HH + e * 2);
        const int k = e * 2;
        hbuf[1][0][(k >> 6) * 36 + ((k & 63) >> 1)] = h2(u[0], u[1]);
    }
    if (tid < 64) {
        const float2_t u = *(const float2_t*)(inputs +
                              (size_t)(bp * SS) * IN + tid * 2);
        xh[0][0][(tid >> 3) * 12 + (tid & 7)] = h2(u[0], u[1]);
    } else if (tid < 128) {
        const int e = tid - 64;
        const float2_t u = *(const float2_t*)(inputs +
                              (size_t)(bq * SS) * IN + e * 2);
        xh[1][0][(e >> 3) * 12 + (e & 7)] = h2(u[0], u[1]);
    }
    __syncthreads();

    for (int t = 0; t < SS; ++t) {
        const int pc = t & 1;

        // ---- Phase A/B: batch p compute + finalize + publish (tag t+1)
        float acc[4] = {0.f, 0.f, 0.f, 0.f};
        float oa = 0.f;
        GEMV_PHASE(hbuf[0][pc], xh[0][pc]);
        FINALIZE(bp, 0, t);

        // ---- Phase C: pull partner h_q^t (published one phase ago -> the
        //      round trip is hidden under phase A). t=0 comes from h0 init.
        if (t > 0) POLL(bq, 1, t);

        // ---- x prefetch for t+1, both batches (waves 4-5; latency hidden
        //      under the pollers holding the barrier)
        if (t + 1 < SS) {
            if (tid >= 256 && tid < 320) {
                const int e = tid - 256;
                const float2_t u = *(const float2_t*)(inputs +
                                      (size_t)(bp * SS + t + 1) * IN + e * 2);
                xh[0][(t + 1) & 1][(e >> 3) * 12 + (e & 7)] = h2(u[0], u[1]);
            } else if (tid >= 320 && tid < 384) {
                const int e = tid - 320;
                const float2_t u = *(const float2_t*)(inputs +
                                      (size_t)(bq * SS + t + 1) * IN + e * 2);
                xh[1][(t + 1) & 1][(e >> 3) * 12 + (e & 7)] = h2(u[0], u[1]);
            }
        }
        __syncthreads();

        // ---- Phase E/F: batch q compute + finalize + publish (tag t+1)
        acc[0] = acc[1] = acc[2] = acc[3] = 0.f;
        oa = 0.f;
        GEMV_PHASE(hbuf[1][pc], xh[1][pc]);
        FINALIZE(bq, 1, t);

        // ---- Phase G: pull partner h_p^{t+1} (published before phase C;
        //      round trip hidden under phase E).
        POLL(bp, 0, t + 1);
        __syncthreads();
    }

    // ---- epilogue: pull partner half of h_q^SS, then output row S-1 for
    //      both batches from h^SS (parity 0).
    POLL(bq, 1, SS);
    __syncthreads();

    #pragma unroll
    for (int s = 0; s < 2; ++s) {
        float oa = 0.f;
        const half2_t* hb = &hbuf[s][0][c * 36];
        #pragma unroll
        for (int kb = 0; kb < 8; ++kb) {
            const half8_t hv = *(const half8_t*)(hb + kb * 4);
            oa = fdot2f(wo[kb * 4 + 0], __builtin_shufflevector(hv, hv, 0, 1), oa);
            oa = fdot2f(wo[kb * 4 + 1], __builtin_shufflevector(hv, hv, 2, 3), oa);
            oa = fdot2f(wo[kb * 4 + 2], __builtin_shufflevector(hv, hv, 4, 5), oa);
            oa = fdot2f(wo[kb * 4 + 3], __builtin_shufflevector(hv, hv, 6, 7), oa);
        }
        oa += __shfl_xor(oa, 1);
        oa += __shfl_xor(oa, 2);
        oa += __shfl_xor(oa, 4);
        if (c == 0)
            outp[(size_t)((bp + s) * SS + (SS - 1)) * OO + og] = oa + bo;
    }
}

// ---------------------------------------------------------------- launcher
extern "C" void kernel_launch(void* const* d_in, const int* in_sizes, int n_in,
                              void* d_out, int out_size, void* d_ws, size_t ws_size,
                              hipStream_t stream) {
    const float* inputs  = (const float*)d_in[0];
    const float* h0      = (const float*)d_in[1];
    const float* W_in_w  = (const float*)d_in[2];
    const float* W_in_b  = (const float*)d_in[3];
    const float* W_rec_w = (const float*)d_in[4];
    const float* W_out_w = (const float*)d_in[5];
    const float* W_out_b = (const float*)d_in[6];

    float* out    = (float*)d_out;                   // fp32 outputs
    float* hfinal = out + (size_t)BB * SS * OO;      // fp32 h_final
    u64* hex      = (u64*)d_ws;                      // 256 KiB exchange

    rnn_fused<<<dim3(BB), dim3(512), 0, stream>>>(
        inputs, h0, W_in_w, W_in_b, W_rec_w, W_out_w, W_out_b,
        out, hfinal, hex);
}